// Round 3
// baseline (1245.819 us; speedup 1.0000x reference)
//
#include <hip/hip_runtime.h>
#include <hip/hip_bf16.h>

typedef unsigned short u16;
typedef __attribute__((ext_vector_type(8))) short bf16x8;
typedef __attribute__((ext_vector_type(4))) float f32x4;

#define Bc 4
#define Sc 8192
#define Fc 512
#define Nc 64
#define Hc 2048
#define Tc 32768
#define SIXF 3072

__device__ __forceinline__ u16 f2bf(float v) {
  __hip_bfloat16 h = __float2bfloat16(v);
  return *reinterpret_cast<u16*>(&h);
}
__device__ __forceinline__ float bf2f(u16 u) {
  return __uint_as_float(((unsigned)u) << 16);
}
__device__ __forceinline__ float ldf(const void* p, long i, int bf) {
  return bf ? bf2f(((const u16*)p)[i]) : ((const float*)p)[i];
}

// ---------- dtype detection: fp32 low-halves look like wild-exponent bf16 ----------
__global__ void k_detect(const u16* __restrict__ x, int* __restrict__ flag) {
  if (threadIdx.x == 0) {
    int cnt = 0;
    for (int i = 0; i < 256; ++i) {
      int e = (x[i] >> 7) & 0xFF;
      cnt += (e >= 130);
    }
    *flag = (cnt >= 16) ? 0 : 1;   // 1 = bf16 inputs, 0 = fp32 inputs
  }
}

__global__ void k_convert(const void* __restrict__ src, float* __restrict__ dst,
                          int n, const int* __restrict__ flag) {
  int bf = *flag;
  int i = blockIdx.x * blockDim.x + threadIdx.x;
  int stride = gridDim.x * blockDim.x;
  for (int j = i; j < n; j += stride) dst[j] = ldf(src, j, bf);
}

// ---------- precompute ----------
__global__ __launch_bounds__(256) void k_mods(const void* __restrict__ cond,
                                              const void* __restrict__ ada_w,
                                              const void* __restrict__ ada_b,
                                              const int* __restrict__ flag,
                                              float* __restrict__ mods) {
  int bf = *flag;
  int b = blockIdx.y;
  int col = blockIdx.x * 256 + threadIdx.x;
  __shared__ float sc[Fc];
  for (int i = threadIdx.x; i < Fc; i += 256) {
    float c = ldf(cond, b * Fc + i, bf);
    sc[i] = c / (1.f + expf(-c));
  }
  __syncthreads();
  float acc = 0.f;
  for (int f = 0; f < Fc; ++f) acc = fmaf(sc[f], ldf(ada_w, (long)f * SIXF + col, bf), acc);
  mods[b * SIXF + col] = acc + ldf(ada_b, col, bf);
}

// Abar fp32 + Wbu packed bf16 [K/8=64][256][8]
__global__ void k_prep(const void* lAf, const void* Aif, const void* Brf, const void* Bif, const void* ldtf,
                       const void* lAb, const void* Aib, const void* Brb, const void* Bib, const void* ldtb,
                       const int* __restrict__ flag,
                       u16* __restrict__ Wbup, float* __restrict__ Abar) {
  int bf = *flag;
  int dir = blockIdx.x;
  int n = threadIdx.x;   // 64
  const void* lA = dir ? lAb : lAf;
  const void* Ai = dir ? Aib : Aif;
  const void* Br = dir ? Brb : Brf;
  const void* Bi = dir ? Bib : Bif;
  const void* ld = dir ? ldtb : ldtf;
  float dt  = expf(ldf(ld, n, bf));
  float Are = -expf(ldf(lA, n, bf));
  float Aim = ldf(Ai, n, bf);
  float er  = expf(Are * dt);
  float abr = er * cosf(Aim * dt);
  float abi = er * sinf(Aim * dt);
  Abar[(dir * Nc + n) * 2 + 0] = abr;
  Abar[(dir * Nc + n) * 2 + 1] = abi;
  float dr = Are + 1e-8f, di = Aim;
  float den = dr * dr + di * di;
  float nr = abr - 1.f, ni = abi;
  float cr = (nr * dr + ni * di) / den;
  float ci = (ni * dr - nr * di) / den;
  int col_re = dir * 128 + n, col_im = dir * 128 + 64 + n;
  for (int f = 0; f < Fc; ++f) {
    float br = ldf(Br, n * Fc + f, bf), bi = ldf(Bi, n * Fc + f, bf);
    Wbup[(((f >> 3) * 256) + col_re) * 8 + (f & 7)] = f2bf(cr * br - ci * bi);
    Wbup[(((f >> 3) * 256) + col_im) * 8 + (f & 7)] = f2bf(cr * bi + ci * br);
  }
}

// P2 packed bf16 [512/8][512][8]
__global__ __launch_bounds__(256) void k_P2p(const void* Df, const void* Db, const void* pw,
                                             const int* __restrict__ flag, u16* __restrict__ P2p) {
  int bf = *flag;
  int idx = blockIdx.x * 256 + threadIdx.x;     // 262144
  int f1 = idx >> 9, fo = idx & 511;
  float v = ldf(Df, f1, bf) * ldf(pw, (long)f1 * Fc + fo, bf) +
            ldf(Db, f1, bf) * ldf(pw, (long)(Fc + f1) * Fc + fo, bf);
  P2p[(((f1 >> 3) * Fc) + fo) * 8 + (f1 & 7)] = f2bf(v);
}

// G packed bf16 [256/8][512][8]; row k=dir*128+c*64+n
__global__ __launch_bounds__(256) void k_Gp(const void* Cref, const void* Cimf,
                                            const void* Creb, const void* Cimb,
                                            const void* pw, const int* __restrict__ flag,
                                            u16* __restrict__ Gp) {
  int bf = *flag;
  int k = blockIdx.x;                 // 256
  int dir = k >> 7, c = (k >> 6) & 1, n = k & 63;
  const void* C = dir ? (c ? Cimb : Creb) : (c ? Cimf : Cref);
  float sgn = c ? -1.f : 1.f;
  int t = threadIdx.x;
  float a0 = 0.f, a1 = 0.f;
  for (int f1 = 0; f1 < Fc; ++f1) {
    float cv = sgn * ldf(C, f1 * Nc + n, bf);
    long base = (long)(dir * Fc + f1) * Fc;
    a0 = fmaf(cv, ldf(pw, base + t, bf), a0);
    a1 = fmaf(cv, ldf(pw, base + t + 256, bf), a1);
  }
  Gp[(((k >> 3) * Fc) + t) * 8 + (k & 7)] = f2bf(a0);
  Gp[(((k >> 3) * Fc) + t + 256) * 8 + (k & 7)] = f2bf(a1);
}

// generic raw [K,N] -> packed bf16 [K/8][N][8]
__global__ __launch_bounds__(256) void k_Wpack(const void* __restrict__ src, const int* __restrict__ flag,
                                               int log2N, u16* __restrict__ dst) {
  int bf = *flag;
  long i = (long)blockIdx.x * 256 + threadIdx.x;
  int Nn = 1 << log2N;
  long k = i >> log2N;
  int n = (int)(i & (Nn - 1));
  dst[(((k >> 3) << log2N) + n) * 8 + (k & 7)] = f2bf(ldf(src, i, bf));
}

// ---------- LayerNorm + AdaLN ----------
// src indexed at (src_tok_base + lt); mods batch = b0 + (lt>>13)
__global__ __launch_bounds__(256) void k_ln(const void* __restrict__ src, int srcmode,
                                            long src_tok_base, int b0,
                                            const int* __restrict__ flag,
                                            const float* __restrict__ mods,
                                            int sh_base, int sc_base,
                                            u16* __restrict__ dst) {
  int bf = srcmode ? 1 : *flag;
  long lt = blockIdx.x;
  int b = b0 + (int)(lt >> 13);
  int t = threadIdx.x;
  long si = (src_tok_base + lt) * Fc;
  float x0 = ldf(src, si + t, bf);
  float x1 = ldf(src, si + t + 256, bf);
  float s = x0 + x1, qq = x0 * x0 + x1 * x1;
  for (int o = 32; o; o >>= 1) { s += __shfl_down(s, o); qq += __shfl_down(qq, o); }
  __shared__ float ss[4], sq[4];
  int w = t >> 6;
  if ((t & 63) == 0) { ss[w] = s; sq[w] = qq; }
  __syncthreads();
  float S = ss[0] + ss[1] + ss[2] + ss[3];
  float Q = sq[0] + sq[1] + sq[2] + sq[3];
  float mu = S * (1.f / Fc);
  float var = Q * (1.f / Fc) - mu * mu;
  float rs = rsqrtf(var + 1e-5f);
  const float* mb = mods + b * SIXF;
  float h0 = (x0 - mu) * rs * (1.f + mb[sc_base + t]) + mb[sh_base + t];
  float h1 = (x1 - mu) * rs * (1.f + mb[sc_base + t + 256]) + mb[sh_base + t + 256];
  dst[lt * Fc + t] = f2bf(h0);
  dst[lt * Fc + t + 256] = f2bf(h1);
}

// ---------- MFMA GEMM core ----------
struct Smem { u16 As[128 * 64]; u16 Ws[64 * 128]; };

__device__ __forceinline__ void mfma_gemm(Smem& sm, const u16* __restrict__ A, long row0, int K,
                                          const u16* __restrict__ Wp, int N, int col0,
                                          f32x4 (&acc)[4][4]) {
  const int tid = threadIdx.x;
  const int l = tid & 63;
  const int q = l >> 4, li = l & 15;
  const int w = tid >> 6;
  const int wm = (w >> 1) << 6, wn = (w & 1) << 6;
  for (int k0 = 0; k0 < K; k0 += 64) {
    __syncthreads();
#pragma unroll
    for (int it = 0; it < 4; ++it) {
      int c = (it << 8) + tid;
      int m = c >> 3, kc = c & 7;
      uint4 v = *(const uint4*)(A + (row0 + m) * (long)K + k0 + (kc << 3));
      *(uint4*)(sm.As + (((m << 3) + (kc ^ (m & 7))) << 3)) = v;
    }
#pragma unroll
    for (int it = 0; it < 4; ++it) {
      int c = (it << 8) + tid;
      uint4 v = *(const uint4*)(Wp + ((((long)(k0 >> 3) + (c >> 7)) * N + col0 + (c & 127)) << 3));
      *(uint4*)(sm.Ws + ((long)c << 3)) = v;
    }
    __syncthreads();
#pragma unroll
    for (int ks = 0; ks < 2; ++ks) {
      bf16x8 af[4], bw[4];
#pragma unroll
      for (int mt = 0; mt < 4; ++mt) {
        int mrow = wm + (mt << 4) + li;
        af[mt] = *(const bf16x8*)(sm.As + (((mrow << 3) + (((ks << 2) + q) ^ (mrow & 7))) << 3));
      }
#pragma unroll
      for (int nt = 0; nt < 4; ++nt) {
        int n = wn + (nt << 4) + li;
        bw[nt] = *(const bf16x8*)(sm.Ws + ((((((ks << 2) + q) << 7) + n)) << 3));
      }
#pragma unroll
      for (int mt = 0; mt < 4; ++mt)
#pragma unroll
        for (int nt = 0; nt < 4; ++nt)
          acc[mt][nt] = __builtin_amdgcn_mfma_f32_16x16x32_bf16(af[mt], bw[nt], acc[mt][nt], 0, 0, 0);
    }
  }
}

// Bu GEMM: h[nb*8192,512] @ Wbu -> Bu[dir][lb][n][s][2] (bwd s flipped)
__global__ __launch_bounds__(256) void k_gemm_bu(const u16* __restrict__ h,
                                                 const u16* __restrict__ Wbup,
                                                 int nb, float* __restrict__ Bu) {
  __shared__ Smem sm;
  f32x4 acc[4][4] = {};
  long row0 = (long)blockIdx.y * 128;
  int col0 = blockIdx.x << 7;
  mfma_gemm(sm, h, row0, Fc, Wbup, 256, col0, acc);
  const int l = threadIdx.x & 63, q = l >> 4, li = l & 15;
  const int w = threadIdx.x >> 6;
  const int wm = (w >> 1) << 6, wn = (w & 1) << 6;
#pragma unroll
  for (int mt = 0; mt < 4; ++mt) {
#pragma unroll
    for (int nt = 0; nt < 4; ++nt) {
      int col = col0 + wn + (nt << 4) + li;
      int dir = col >> 7, cc = (col >> 6) & 1, n = col & 63;
#pragma unroll
      for (int r = 0; r < 4; ++r) {
        long lt = row0 + wm + (mt << 4) + (q << 2) + r;
        int lb = (int)(lt >> 13), s = (int)(lt & 8191);
        int spos = dir ? (Sc - 1 - s) : s;
        Bu[((((long)dir * nb + lb) * Nc + n) * Sc + spos) * 2 + cc] = acc[mt][nt][r];
      }
    }
  }
}

// chunked complex linear scan, in-place on Bu. One block per (dir,lb,n).
__global__ __launch_bounds__(256) void k_scan(float* __restrict__ Bu, const float* __restrict__ Abar,
                                              int nb) {
  int blk = blockIdx.x;                  // 2*nb*64
  int per_dir = nb * 64;
  int dir = blk / per_dir;
  int rem = blk - dir * per_dir;
  int lb = rem >> 6, n = rem & 63;
  float ar = Abar[(dir * Nc + n) * 2 + 0];
  float ai = Abar[(dir * Nc + n) * 2 + 1];
  float* base = Bu + (((long)dir * nb + lb) * Nc + n) * Sc * 2;
  int t = threadIdx.x;
  float2 loc[32];
  float lr = 0.f, li = 0.f;
  const float2* bp = (const float2*)base + t * 32;
#pragma unroll
  for (int j = 0; j < 32; ++j) {
    float2 v = bp[j];
    loc[j] = v;
    float nr = fmaf(ar, lr, fmaf(-ai, li, v.x));
    float ni = fmaf(ar, li, fmaf(ai, lr, v.y));
    lr = nr; li = ni;
  }
  __shared__ float sr[256], si[256];
  float pr = ar, pi = ai;
  for (int k = 0; k < 5; ++k) { float t2 = pr * pr - pi * pi; pi = 2.f * pr * pi; pr = t2; }  // a^32
  float vr = lr, vi = li;
  for (int step = 1; step < 256; step <<= 1) {
    sr[t] = vr; si[t] = vi;
    __syncthreads();
    if (t >= step) {
      float orr = sr[t - step], oii = si[t - step];
      vr = vr + pr * orr - pi * oii;
      vi = vi + pr * oii + pi * orr;
    }
    __syncthreads();
    float t2 = pr * pr - pi * pi; pi = 2.f * pr * pi; pr = t2;
  }
  sr[t] = vr; si[t] = vi;
  __syncthreads();
  float xr = (t == 0) ? 0.f : sr[t - 1];
  float xi = (t == 0) ? 0.f : si[t - 1];
  float2* op = (float2*)base + t * 32;
#pragma unroll
  for (int j = 0; j < 32; ++j) {
    float2 v = loc[j];
    float nr = fmaf(ar, xr, fmaf(-ai, xi, v.x));
    float ni = fmaf(ar, xi, fmaf(ai, xr, v.y));
    xr = nr; xi = ni;
    op[j] = make_float2(xr, xi);
  }
}

// gather xs -> token-major bf16 hi/lo [nb*8192,256]
__global__ __launch_bounds__(256) void k_xs_t(const float* __restrict__ xs, int nb,
                                              u16* __restrict__ xh, u16* __restrict__ xl) {
  long lt = blockIdx.x;
  int lb = (int)(lt >> 13), s = (int)(lt & 8191);
  int t = threadIdx.x;
  int dir = t >> 7, cc = (t >> 6) & 1, n = t & 63;
  int spos = dir ? (Sc - 1 - s) : s;
  float v = xs[((((long)dir * nb + lb) * Nc + n) * Sc + spos) * 2 + cc];
  u16 hi = f2bf(v);
  xh[lt * 256 + t] = hi;
  xl[lt * 256 + t] = f2bf(v - bf2f(hi));
}

// out1 = bf16( x + g1*(xs@G + h@P2 + pb) )
__global__ __launch_bounds__(256) void k_gemm_y(const u16* __restrict__ xh, const u16* __restrict__ xl,
                                                const u16* __restrict__ Gp,
                                                const u16* __restrict__ h, const u16* __restrict__ P2p,
                                                const void* __restrict__ xraw, long tok_base, int b0,
                                                const int* __restrict__ flag,
                                                const float* __restrict__ mods, const float* __restrict__ pb,
                                                u16* __restrict__ out1) {
  __shared__ Smem sm;
  f32x4 acc[4][4] = {};
  long row0 = (long)blockIdx.y * 128;
  int col0 = blockIdx.x << 7;
  mfma_gemm(sm, xh, row0, 256, Gp, Fc, col0, acc);
  mfma_gemm(sm, xl, row0, 256, Gp, Fc, col0, acc);
  mfma_gemm(sm, h, row0, Fc, P2p, Fc, col0, acc);
  int bf = *flag;
  const int l = threadIdx.x & 63, q = l >> 4, li = l & 15;
  const int w = threadIdx.x >> 6;
  const int wm = (w >> 1) << 6, wn = (w & 1) << 6;
#pragma unroll
  for (int mt = 0; mt < 4; ++mt) {
#pragma unroll
    for (int r = 0; r < 4; ++r) {
      long lt = row0 + wm + (mt << 4) + (q << 2) + r;
      int b = b0 + (int)(lt >> 13);
      const float* mb = mods + b * SIXF + 2 * Fc;
#pragma unroll
      for (int nt = 0; nt < 4; ++nt) {
        int col = col0 + wn + (nt << 4) + li;
        float xv = ldf(xraw, (tok_base + lt) * Fc + col, bf);
        out1[lt * Fc + col] = f2bf(xv + mb[col] * (acc[mt][nt][r] + pb[col]));
      }
    }
  }
}

__device__ __forceinline__ float gelu_t(float u) {
  float inner = 0.7978845608028654f * fmaf(0.044715f * u * u, u, u);
  return 0.5f * u * (1.f + tanhf(inner));
}

// tbuf[lt-crow0, 2048] = bf16(gelu(h2@W1 + b1))
__global__ __launch_bounds__(256) void k_mlp1(const u16* __restrict__ h2, const u16* __restrict__ W1p,
                                              const float* __restrict__ b1, long crow0,
                                              u16* __restrict__ tbuf) {
  __shared__ Smem sm;
  f32x4 acc[4][4] = {};
  long row0 = crow0 + (long)blockIdx.y * 128;
  int col0 = blockIdx.x << 7;
  mfma_gemm(sm, h2, row0, Fc, W1p, Hc, col0, acc);
  const int l = threadIdx.x & 63, q = l >> 4, li = l & 15;
  const int w = threadIdx.x >> 6;
  const int wm = (w >> 1) << 6, wn = (w & 1) << 6;
#pragma unroll
  for (int mt = 0; mt < 4; ++mt) {
#pragma unroll
    for (int r = 0; r < 4; ++r) {
      long lr2 = row0 - crow0 + wm + (mt << 4) + (q << 2) + r;
#pragma unroll
      for (int nt = 0; nt < 4; ++nt) {
        int col = col0 + wn + (nt << 4) + li;
        tbuf[lr2 * Hc + col] = f2bf(gelu_t(acc[mt][nt][r] + b1[col]));
      }
    }
  }
}

// out = out1 + g2*(tbuf@W2 + b2) -> d_out
__global__ __launch_bounds__(256) void k_mlp2(const u16* __restrict__ tbuf, const u16* __restrict__ W2p,
                                              const float* __restrict__ b2, const u16* __restrict__ out1,
                                              const float* __restrict__ mods, long crow0,
                                              long tok_base, int b0,
                                              const int* __restrict__ flag, void* __restrict__ dout) {
  __shared__ Smem sm;
  f32x4 acc[4][4] = {};
  long lrow0 = (long)blockIdx.y * 128;
  int col0 = blockIdx.x << 7;
  mfma_gemm(sm, tbuf, lrow0, Hc, W2p, Fc, col0, acc);
  int bf = *flag;
  const int l = threadIdx.x & 63, q = l >> 4, li = l & 15;
  const int w = threadIdx.x >> 6;
  const int wm = (w >> 1) << 6, wn = (w & 1) << 6;
#pragma unroll
  for (int mt = 0; mt < 4; ++mt) {
#pragma unroll
    for (int r = 0; r < 4; ++r) {
      long lt = crow0 + lrow0 + wm + (mt << 4) + (q << 2) + r;   // pass-local token
      int b = b0 + (int)(lt >> 13);
      const float* mb = mods + b * SIXF + 5 * Fc;
#pragma unroll
      for (int nt = 0; nt < 4; ++nt) {
        int col = col0 + wn + (nt << 4) + li;
        float v = bf2f(out1[lt * Fc + col]) + mb[col] * (acc[mt][nt][r] + b2[col]);
        long oi = (tok_base + lt) * Fc + col;
        if (bf) ((u16*)dout)[oi] = f2bf(v);
        else    ((float*)dout)[oi] = v;
      }
    }
  }
}

extern "C" void kernel_launch(void* const* d_in, const int* in_sizes, int n_in,
                              void* d_out, int out_size, void* d_ws, size_t ws_size,
                              hipStream_t stream) {
  char* ws = (char*)d_ws;
  size_t off = 0;
  auto alloc = [&](size_t bytes) -> char* {
    char* p = ws + off;
    off += (bytes + 255) & ~(size_t)255;
    return p;
  };
  int*   flag = (int*)  alloc(4);
  float* mods = (float*)alloc((size_t)Bc * SIXF * 4);
  float* Abar = (float*)alloc(2 * Nc * 2 * 4);
  float* pbf  = (float*)alloc(Fc * 4);
  float* b1f  = (float*)alloc(Hc * 4);
  float* b2f  = (float*)alloc(Fc * 4);
  u16* Wbup = (u16*)alloc((size_t)Fc * 256 * 2);
  u16* Gp   = (u16*)alloc((size_t)256 * Fc * 2);
  u16* P2p  = (u16*)alloc((size_t)Fc * Fc * 2);
  u16* W1p  = (u16*)alloc((size_t)Fc * Hc * 2);
  u16* W2p  = (u16*)alloc((size_t)Hc * Fc * 2);
  size_t off_static = off;

  // per-batch dynamic unit: 8192 tokens
  const size_t U = (size_t)Sc * Fc * 2;   // 8.39 MB (bf16 [8192,512])
  // choose nb (batches per pass): dynamic need = nb * 4U (h, Bu, xst(hi+lo), out1)
  int nb = 4;
  while (nb > 1 && off_static + (size_t)nb * 4 * U + 4096 > ws_size) nb >>= 1;

  u16*   h    = (u16*)  alloc((size_t)nb * U);            // also tbuf chunk
  float* Bu   = (float*)alloc((size_t)nb * U);            // also h2
  u16*   xh   = (u16*)  alloc((size_t)nb * U / 2);
  u16*   xl   = (u16*)  alloc((size_t)nb * U / 2);
  u16*   out1 = (u16*)  alloc((size_t)nb * U);
  u16* tch = h;
  u16* h2  = (u16*)Bu;

  // dtype detect + bias conversions + packed weights (pass-independent)
  k_detect<<<1, 64, 0, stream>>>((const u16*)d_in[0], flag);
  k_convert<<<2, 256, 0, stream>>>(d_in[19], pbf, Fc, flag);
  k_convert<<<8, 256, 0, stream>>>(d_in[23], b1f, Hc, flag);
  k_convert<<<2, 256, 0, stream>>>(d_in[25], b2f, Fc, flag);
  k_mods<<<dim3(SIXF / 256, Bc), 256, 0, stream>>>(d_in[1], d_in[20], d_in[21], flag, mods);
  k_prep<<<2, 64, 0, stream>>>(d_in[2], d_in[3], d_in[4], d_in[5], d_in[9],
                               d_in[10], d_in[11], d_in[12], d_in[13], d_in[17],
                               flag, Wbup, Abar);
  k_P2p<<<(Fc * Fc) / 256, 256, 0, stream>>>(d_in[8], d_in[16], d_in[18], flag, P2p);
  k_Gp<<<256, 256, 0, stream>>>(d_in[6], d_in[7], d_in[14], d_in[15], d_in[18], flag, Gp);
  k_Wpack<<<(Fc * Hc) / 256, 256, 0, stream>>>(d_in[22], flag, 11, W1p);
  k_Wpack<<<(Hc * Fc) / 256, 256, 0, stream>>>(d_in[24], flag, 9, W2p);

  for (int b0 = 0; b0 < Bc; b0 += nb) {
    long tok_base = (long)b0 * Sc;
    long rows = (long)nb * Sc;
    // LN1 + modulation
    k_ln<<<rows, 256, 0, stream>>>(d_in[0], 0, tok_base, b0, flag, mods, 0, Fc, h);
    // S5: Bu GEMM, scan, gather (hi/lo)
    k_gemm_bu<<<dim3(2, rows / 128), 256, 0, stream>>>(h, Wbup, nb, Bu);
    k_scan<<<2 * nb * 64, 256, 0, stream>>>(Bu, Abar, nb);
    k_xs_t<<<rows, 256, 0, stream>>>(Bu, nb, xh, xl);
    // projection + residual
    k_gemm_y<<<dim3(Fc / 128, rows / 128), 256, 0, stream>>>(xh, xl, Gp, h, P2p,
                                                             d_in[0], tok_base, b0, flag, mods, pbf, out1);
    // LN2 (out1 -> h2, overlays Bu which is now dead)
    k_ln<<<rows, 256, 0, stream>>>(out1, 1, 0, b0, flag, mods, 3 * Fc, 4 * Fc, h2);
    // MLP in 4 row-chunks; tbuf chunk overlays h (dead after gemm_y)
    long RC = rows / 4;
    for (int ch = 0; ch < 4; ++ch) {
      long crow0 = ch * RC;
      k_mlp1<<<dim3(Hc / 128, RC / 128), 256, 0, stream>>>(h2, W1p, b1f, crow0, tch);
      k_mlp2<<<dim3(Fc / 128, RC / 128), 256, 0, stream>>>(tch, W2p, b2f, out1, mods, crow0,
                                                           tok_base, b0, flag, d_out);
    }
  }
  (void)n_in; (void)out_size; (void)in_sizes;
}

// Round 4
// 830.509 us; speedup vs baseline: 1.5001x; 1.5001x over previous
//
#include <hip/hip_runtime.h>
#include <hip/hip_bf16.h>

typedef unsigned short u16;
typedef __attribute__((ext_vector_type(8))) short bf16x8;
typedef __attribute__((ext_vector_type(4))) float f32x4;

#define Bc 4
#define Sc 8192
#define Fc 512
#define Nc 64
#define Hc 2048
#define Tc 32768
#define SIXF 3072

__device__ __forceinline__ u16 f2bf(float v) {
  __hip_bfloat16 h = __float2bfloat16(v);
  return *reinterpret_cast<u16*>(&h);
}
__device__ __forceinline__ float bf2f(u16 u) {
  return __uint_as_float(((unsigned)u) << 16);
}
__device__ __forceinline__ float ldf(const void* p, long i, int bf) {
  return bf ? bf2f(((const u16*)p)[i]) : ((const float*)p)[i];
}

// ---------- dtype detection ----------
__global__ void k_detect(const u16* __restrict__ x, int* __restrict__ flag) {
  if (threadIdx.x == 0) {
    int cnt = 0;
    for (int i = 0; i < 256; ++i) {
      int e = (x[i] >> 7) & 0xFF;
      cnt += (e >= 130);
    }
    *flag = (cnt >= 16) ? 0 : 1;   // 1 = bf16 inputs, 0 = fp32
  }
}

__global__ void k_convert(const void* __restrict__ src, float* __restrict__ dst,
                          int n, const int* __restrict__ flag) {
  int bf = *flag;
  int i = blockIdx.x * blockDim.x + threadIdx.x;
  int stride = gridDim.x * blockDim.x;
  for (int j = i; j < n; j += stride) dst[j] = ldf(src, j, bf);
}

// ---------- mods: init with ada_b, then f-chunked atomic accumulation ----------
__global__ __launch_bounds__(256) void k_mods_init(const void* __restrict__ ada_b,
                                                   const int* __restrict__ flag,
                                                   float* __restrict__ mods) {
  int bf = *flag;
  int col = blockIdx.x * 256 + threadIdx.x;   // grid 12
  float v = ldf(ada_b, col, bf);
  for (int b = 0; b < Bc; ++b) mods[b * SIXF + col] = v;
}

__global__ __launch_bounds__(256) void k_mods2(const void* __restrict__ cond,
                                               const void* __restrict__ ada_w,
                                               const int* __restrict__ flag,
                                               float* __restrict__ mods) {
  int bf = *flag;
  int b = blockIdx.y;
  int f0 = blockIdx.z * 128;
  int col = blockIdx.x * 256 + threadIdx.x;
  __shared__ float sc[128];
  for (int i = threadIdx.x; i < 128; i += 256) {
    float c = ldf(cond, b * Fc + f0 + i, bf);
    sc[i] = c / (1.f + expf(-c));
  }
  __syncthreads();
  float acc = 0.f;
  for (int f = 0; f < 128; ++f) acc = fmaf(sc[f], ldf(ada_w, (long)(f0 + f) * SIXF + col, bf), acc);
  atomicAdd(&mods[b * SIXF + col], acc);
}

// ---------- Abar + Wbu packed, f-chunked ----------
__global__ void k_prep(const void* lAf, const void* Aif, const void* Brf, const void* Bif, const void* ldtf,
                       const void* lAb, const void* Aib, const void* Brb, const void* Bib, const void* ldtb,
                       const int* __restrict__ flag,
                       u16* __restrict__ Wbup, float* __restrict__ Abar) {
  int bf = *flag;
  int dir = blockIdx.x;
  int f0 = blockIdx.y * 64;     // grid (2, 8)
  int n = threadIdx.x;          // 64
  const void* lA = dir ? lAb : lAf;
  const void* Ai = dir ? Aib : Aif;
  const void* Br = dir ? Brb : Brf;
  const void* Bi = dir ? Bib : Bif;
  const void* ld = dir ? ldtb : ldtf;
  float dt  = expf(ldf(ld, n, bf));
  float Are = -expf(ldf(lA, n, bf));
  float Aim = ldf(Ai, n, bf);
  float er  = expf(Are * dt);
  float abr = er * cosf(Aim * dt);
  float abi = er * sinf(Aim * dt);
  if (blockIdx.y == 0) {
    Abar[(dir * Nc + n) * 2 + 0] = abr;
    Abar[(dir * Nc + n) * 2 + 1] = abi;
  }
  float dr = Are + 1e-8f, di = Aim;
  float den = dr * dr + di * di;
  float nr = abr - 1.f, ni = abi;
  float cr = (nr * dr + ni * di) / den;
  float ci = (ni * dr - nr * di) / den;
  int col_re = dir * 128 + n, col_im = dir * 128 + 64 + n;
  for (int f = f0; f < f0 + 64; ++f) {
    float br = ldf(Br, n * Fc + f, bf), bi = ldf(Bi, n * Fc + f, bf);
    Wbup[(((f >> 3) * 256) + col_re) * 8 + (f & 7)] = f2bf(cr * br - ci * bi);
    Wbup[(((f >> 3) * 256) + col_im) * 8 + (f & 7)] = f2bf(cr * bi + ci * br);
  }
}

// P2 packed bf16 [512/8][512][8]
__global__ __launch_bounds__(256) void k_P2p(const void* Df, const void* Db, const void* pw,
                                             const int* __restrict__ flag, u16* __restrict__ P2p) {
  int bf = *flag;
  int idx = blockIdx.x * 256 + threadIdx.x;
  int f1 = idx >> 9, fo = idx & 511;
  float v = ldf(Df, f1, bf) * ldf(pw, (long)f1 * Fc + fo, bf) +
            ldf(Db, f1, bf) * ldf(pw, (long)(Fc + f1) * Fc + fo, bf);
  P2p[(((f1 >> 3) * Fc) + fo) * 8 + (f1 & 7)] = f2bf(v);
}

// Cpm bf16 [256][512]: row k=dir*128+c*64+n, Cpm[k][f] = (+Cre|-Cim)[f][n]
__global__ __launch_bounds__(256) void k_Cpm(const void* Cref, const void* Cimf,
                                             const void* Creb, const void* Cimb,
                                             const int* __restrict__ flag, u16* __restrict__ Cpm) {
  int bf = *flag;
  int k = blockIdx.x;
  int dir = k >> 7, c = (k >> 6) & 1, n = k & 63;
  const void* C = dir ? (c ? Cimb : Creb) : (c ? Cimf : Cref);
  float sgn = c ? -1.f : 1.f;
  for (int f = threadIdx.x; f < Fc; f += 256)
    Cpm[k * Fc + f] = f2bf(sgn * ldf(C, (long)f * Nc + n, bf));
}

// generic raw [K,N] -> packed bf16 [K/8][N][8]; one thread per (k8,n)
__global__ __launch_bounds__(256) void k_Wpack(const void* __restrict__ src, const int* __restrict__ flag,
                                               int log2N, u16* __restrict__ dst) {
  int bf = *flag;
  long i = (long)blockIdx.x * 256 + threadIdx.x;     // over (K/8)*N
  int Nn = 1 << log2N;
  long k8 = i >> log2N;
  int n = (int)(i & (Nn - 1));
  u16 tmp[8];
#pragma unroll
  for (int j = 0; j < 8; ++j)
    tmp[j] = f2bf(ldf(src, ((k8 << 3) + j) * (long)Nn + n, bf));
  *(ushort4*)(dst + i * 8)     = *(ushort4*)tmp;
  *(ushort4*)(dst + i * 8 + 4) = *(ushort4*)(tmp + 4);
}

// ---------- LayerNorm + AdaLN ----------
__global__ __launch_bounds__(256) void k_ln(const void* __restrict__ src, int srcmode,
                                            long src_tok_base, int b0,
                                            const int* __restrict__ flag,
                                            const float* __restrict__ mods,
                                            int sh_base, int sc_base,
                                            u16* __restrict__ dst) {
  int bf = srcmode ? 1 : *flag;
  long lt = blockIdx.x;
  int b = b0 + (int)(lt >> 13);
  int t = threadIdx.x;
  long si = (src_tok_base + lt) * Fc;
  float x0 = ldf(src, si + t, bf);
  float x1 = ldf(src, si + t + 256, bf);
  float s = x0 + x1, qq = x0 * x0 + x1 * x1;
  for (int o = 32; o; o >>= 1) { s += __shfl_down(s, o); qq += __shfl_down(qq, o); }
  __shared__ float ss[4], sq[4];
  int w = t >> 6;
  if ((t & 63) == 0) { ss[w] = s; sq[w] = qq; }
  __syncthreads();
  float S = ss[0] + ss[1] + ss[2] + ss[3];
  float Q = sq[0] + sq[1] + sq[2] + sq[3];
  float mu = S * (1.f / Fc);
  float var = Q * (1.f / Fc) - mu * mu;
  float rs = rsqrtf(var + 1e-5f);
  const float* mb = mods + b * SIXF;
  float h0 = (x0 - mu) * rs * (1.f + mb[sc_base + t]) + mb[sh_base + t];
  float h1 = (x1 - mu) * rs * (1.f + mb[sc_base + t + 256]) + mb[sh_base + t + 256];
  dst[lt * Fc + t] = f2bf(h0);
  dst[lt * Fc + t + 256] = f2bf(h1);
}

// ---------- MFMA GEMM core ----------
struct Smem { u16 As[128 * 64]; u16 Ws[64 * 128]; };

__device__ __forceinline__ void mfma_gemm(Smem& sm, const u16* __restrict__ A, long row0, int K,
                                          const u16* __restrict__ Wp, int N, int col0,
                                          f32x4 (&acc)[4][4]) {
  const int tid = threadIdx.x;
  const int l = tid & 63;
  const int q = l >> 4, li = l & 15;
  const int w = tid >> 6;
  const int wm = (w >> 1) << 6, wn = (w & 1) << 6;
  for (int k0 = 0; k0 < K; k0 += 64) {
    __syncthreads();
#pragma unroll
    for (int it = 0; it < 4; ++it) {
      int c = (it << 8) + tid;
      int m = c >> 3, kc = c & 7;
      uint4 v = *(const uint4*)(A + (row0 + m) * (long)K + k0 + (kc << 3));
      *(uint4*)(sm.As + (((m << 3) + (kc ^ (m & 7))) << 3)) = v;
    }
#pragma unroll
    for (int it = 0; it < 4; ++it) {
      int c = (it << 8) + tid;
      uint4 v = *(const uint4*)(Wp + ((((long)(k0 >> 3) + (c >> 7)) * N + col0 + (c & 127)) << 3));
      *(uint4*)(sm.Ws + ((long)c << 3)) = v;
    }
    __syncthreads();
#pragma unroll
    for (int ks = 0; ks < 2; ++ks) {
      bf16x8 af[4], bw[4];
#pragma unroll
      for (int mt = 0; mt < 4; ++mt) {
        int mrow = wm + (mt << 4) + li;
        af[mt] = *(const bf16x8*)(sm.As + (((mrow << 3) + (((ks << 2) + q) ^ (mrow & 7))) << 3));
      }
#pragma unroll
      for (int nt = 0; nt < 4; ++nt) {
        int n = wn + (nt << 4) + li;
        bw[nt] = *(const bf16x8*)(sm.Ws + ((((((ks << 2) + q) << 7) + n)) << 3));
      }
#pragma unroll
      for (int mt = 0; mt < 4; ++mt)
#pragma unroll
        for (int nt = 0; nt < 4; ++nt)
          acc[mt][nt] = __builtin_amdgcn_mfma_f32_16x16x32_bf16(af[mt], bw[nt], acc[mt][nt], 0, 0, 0);
    }
  }
}

// G via MFMA: Cpm[256,512] @ pwp(dir half) -> packed Gp
__global__ __launch_bounds__(256) void k_Gp2(const u16* __restrict__ Cpm, const u16* __restrict__ pwp,
                                             u16* __restrict__ Gp) {
  __shared__ Smem sm;
  f32x4 acc[4][4] = {};
  long row0 = (long)blockIdx.y * 128;
  int col0 = blockIdx.x << 7;
  int dir = (int)(row0 >> 7);
  mfma_gemm(sm, Cpm, row0, Fc, pwp + (size_t)dir * 262144, Fc, col0, acc);
  const int l = threadIdx.x & 63, q = l >> 4, li = l & 15;
  const int w = threadIdx.x >> 6;
  const int wm = (w >> 1) << 6, wn = (w & 1) << 6;
#pragma unroll
  for (int mt = 0; mt < 4; ++mt)
#pragma unroll
    for (int nt = 0; nt < 4; ++nt)
#pragma unroll
      for (int r = 0; r < 4; ++r) {
        int k = (int)row0 + wm + (mt << 4) + (q << 2) + r;
        int col = col0 + wn + (nt << 4) + li;
        Gp[(((k >> 3) * Fc) + col) * 8 + (k & 7)] = f2bf(acc[mt][nt][r]);
      }
}

// Bu GEMM: h[nb*8192,512] @ Wbu -> Bu[dir][lb][n][s][2] (bwd s flipped)
__global__ __launch_bounds__(256) void k_gemm_bu(const u16* __restrict__ h,
                                                 const u16* __restrict__ Wbup,
                                                 int nb, float* __restrict__ Bu) {
  __shared__ Smem sm;
  f32x4 acc[4][4] = {};
  long row0 = (long)blockIdx.y * 128;
  int col0 = blockIdx.x << 7;
  mfma_gemm(sm, h, row0, Fc, Wbup, 256, col0, acc);
  const int l = threadIdx.x & 63, q = l >> 4, li = l & 15;
  const int w = threadIdx.x >> 6;
  const int wm = (w >> 1) << 6, wn = (w & 1) << 6;
#pragma unroll
  for (int mt = 0; mt < 4; ++mt) {
#pragma unroll
    for (int nt = 0; nt < 4; ++nt) {
      int col = col0 + wn + (nt << 4) + li;
      int dir = col >> 7, cc = (col >> 6) & 1, n = col & 63;
#pragma unroll
      for (int r = 0; r < 4; ++r) {
        long lt = row0 + wm + (mt << 4) + (q << 2) + r;
        int lb = (int)(lt >> 13), s = (int)(lt & 8191);
        int spos = dir ? (Sc - 1 - s) : s;
        Bu[((((long)dir * nb + lb) * Nc + n) * Sc + spos) * 2 + cc] = acc[mt][nt][r];
      }
    }
  }
}

// chunked complex linear scan, in-place on Bu (float4 I/O). One block per (dir,lb,n).
__global__ __launch_bounds__(256) void k_scan(float* __restrict__ Bu, const float* __restrict__ Abar,
                                              int nb) {
  int blk = blockIdx.x;
  int per_dir = nb * 64;
  int dir = blk / per_dir;
  int rem = blk - dir * per_dir;
  int lb = rem >> 6, n = rem & 63;
  float ar = Abar[(dir * Nc + n) * 2 + 0];
  float ai = Abar[(dir * Nc + n) * 2 + 1];
  float* base = Bu + (((long)dir * nb + lb) * Nc + n) * Sc * 2;
  int t = threadIdx.x;
  float4 loc[16];
  float lr = 0.f, li = 0.f;
  const float4* bp = (const float4*)base + t * 16;
#pragma unroll
  for (int j = 0; j < 16; ++j) {
    float4 v = bp[j];
    loc[j] = v;
    float nr = fmaf(ar, lr, fmaf(-ai, li, v.x));
    float ni = fmaf(ar, li, fmaf(ai, lr, v.y));
    lr = fmaf(ar, nr, fmaf(-ai, ni, v.z));
    li = fmaf(ar, ni, fmaf(ai, nr, v.w));
  }
  __shared__ float sr[256], si[256];
  float pr = ar, pi = ai;
  for (int k = 0; k < 5; ++k) { float t2 = pr * pr - pi * pi; pi = 2.f * pr * pi; pr = t2; }  // a^32
  float vr = lr, vi = li;
  for (int step = 1; step < 256; step <<= 1) {
    sr[t] = vr; si[t] = vi;
    __syncthreads();
    if (t >= step) {
      float orr = sr[t - step], oii = si[t - step];
      vr = vr + pr * orr - pi * oii;
      vi = vi + pr * oii + pi * orr;
    }
    __syncthreads();
    float t2 = pr * pr - pi * pi; pi = 2.f * pr * pi; pr = t2;
  }
  sr[t] = vr; si[t] = vi;
  __syncthreads();
  float xr = (t == 0) ? 0.f : sr[t - 1];
  float xi = (t == 0) ? 0.f : si[t - 1];
  float4* op = (float4*)base + t * 16;
#pragma unroll
  for (int j = 0; j < 16; ++j) {
    float4 v = loc[j];
    float nr = fmaf(ar, xr, fmaf(-ai, xi, v.x));
    float ni = fmaf(ar, xi, fmaf(ai, xr, v.y));
    xr = fmaf(ar, nr, fmaf(-ai, ni, v.z));
    xi = fmaf(ar, ni, fmaf(ai, nr, v.w));
    float4 o; o.x = nr; o.y = ni; o.z = xr; o.w = xi;
    op[j] = o;
  }
}

// gather xs -> token-major bf16 hi/lo via LDS transpose (32 tokens x 256 cols per block)
__global__ __launch_bounds__(256) void k_xs_t(const float* __restrict__ xs, int nb,
                                              u16* __restrict__ xh, u16* __restrict__ xl) {
  __shared__ float tile[32 * 257];
  long t0 = (long)blockIdx.x * 32;
  int lb = (int)(t0 >> 13);
  int s0 = (int)(t0 & 8191);
  int tid = threadIdx.x;
  int ls = tid & 31;
  int half = (tid >> 5) & 1;      // two cols per wave-instruction
  int wv = tid >> 6;
#pragma unroll 4
  for (int cg = 0; cg < 32; ++cg) {
    int col = cg * 8 + wv * 2 + half;
    int dir = col >> 7, cc = (col >> 6) & 1, n = col & 63;
    int spos = dir ? (Sc - 1 - (s0 + ls)) : (s0 + ls);
    float v = xs[((((long)dir * nb + lb) * Nc + n) * Sc + spos) * 2 + cc];
    tile[ls * 257 + col] = v;
  }
  __syncthreads();
  for (int j = 0; j < 32; ++j) {
    float v = tile[j * 257 + tid];
    u16 hi = f2bf(v);
    long lt = t0 + j;
    xh[lt * 256 + tid] = hi;
    xl[lt * 256 + tid] = f2bf(v - bf2f(hi));
  }
}

// out1 = bf16( x + g1*(xs@G + h@P2 + pb) )
__global__ __launch_bounds__(256) void k_gemm_y(const u16* __restrict__ xh, const u16* __restrict__ xl,
                                                const u16* __restrict__ Gp,
                                                const u16* __restrict__ h, const u16* __restrict__ P2p,
                                                const void* __restrict__ xraw, long tok_base, int b0,
                                                const int* __restrict__ flag,
                                                const float* __restrict__ mods, const float* __restrict__ pb,
                                                u16* __restrict__ out1) {
  __shared__ Smem sm;
  f32x4 acc[4][4] = {};
  long row0 = (long)blockIdx.y * 128;
  int col0 = blockIdx.x << 7;
  mfma_gemm(sm, xh, row0, 256, Gp, Fc, col0, acc);
  mfma_gemm(sm, xl, row0, 256, Gp, Fc, col0, acc);
  mfma_gemm(sm, h, row0, Fc, P2p, Fc, col0, acc);
  int bf = *flag;
  const int l = threadIdx.x & 63, q = l >> 4, li = l & 15;
  const int w = threadIdx.x >> 6;
  const int wm = (w >> 1) << 6, wn = (w & 1) << 6;
#pragma unroll
  for (int mt = 0; mt < 4; ++mt) {
#pragma unroll
    for (int r = 0; r < 4; ++r) {
      long lt = row0 + wm + (mt << 4) + (q << 2) + r;
      int b = b0 + (int)(lt >> 13);
      const float* mb = mods + b * SIXF + 2 * Fc;
#pragma unroll
      for (int nt = 0; nt < 4; ++nt) {
        int col = col0 + wn + (nt << 4) + li;
        float xv = ldf(xraw, (tok_base + lt) * Fc + col, bf);
        out1[lt * Fc + col] = f2bf(xv + mb[col] * (acc[mt][nt][r] + pb[col]));
      }
    }
  }
}

__device__ __forceinline__ float gelu_t(float u) {
  float inner = 0.7978845608028654f * fmaf(0.044715f * u * u, u, u);
  return 0.5f * u * (1.f + tanhf(inner));
}

__global__ __launch_bounds__(256) void k_mlp1(const u16* __restrict__ h2, const u16* __restrict__ W1p,
                                              const float* __restrict__ b1, long crow0,
                                              u16* __restrict__ tbuf) {
  __shared__ Smem sm;
  f32x4 acc[4][4] = {};
  long row0 = crow0 + (long)blockIdx.y * 128;
  int col0 = blockIdx.x << 7;
  mfma_gemm(sm, h2, row0, Fc, W1p, Hc, col0, acc);
  const int l = threadIdx.x & 63, q = l >> 4, li = l & 15;
  const int w = threadIdx.x >> 6;
  const int wm = (w >> 1) << 6, wn = (w & 1) << 6;
#pragma unroll
  for (int mt = 0; mt < 4; ++mt) {
#pragma unroll
    for (int r = 0; r < 4; ++r) {
      long lr2 = row0 - crow0 + wm + (mt << 4) + (q << 2) + r;
#pragma unroll
      for (int nt = 0; nt < 4; ++nt) {
        int col = col0 + wn + (nt << 4) + li;
        tbuf[lr2 * Hc + col] = f2bf(gelu_t(acc[mt][nt][r] + b1[col]));
      }
    }
  }
}

__global__ __launch_bounds__(256) void k_mlp2(const u16* __restrict__ tbuf, const u16* __restrict__ W2p,
                                              const float* __restrict__ b2, const u16* __restrict__ out1,
                                              const float* __restrict__ mods, long crow0,
                                              long tok_base, int b0,
                                              const int* __restrict__ flag, void* __restrict__ dout) {
  __shared__ Smem sm;
  f32x4 acc[4][4] = {};
  long lrow0 = (long)blockIdx.y * 128;
  int col0 = blockIdx.x << 7;
  mfma_gemm(sm, tbuf, lrow0, Hc, W2p, Fc, col0, acc);
  int bf = *flag;
  const int l = threadIdx.x & 63, q = l >> 4, li = l & 15;
  const int w = threadIdx.x >> 6;
  const int wm = (w >> 1) << 6, wn = (w & 1) << 6;
#pragma unroll
  for (int mt = 0; mt < 4; ++mt) {
#pragma unroll
    for (int r = 0; r < 4; ++r) {
      long lt = crow0 + lrow0 + wm + (mt << 4) + (q << 2) + r;
      int b = b0 + (int)(lt >> 13);
      const float* mb = mods + b * SIXF + 5 * Fc;
#pragma unroll
      for (int nt = 0; nt < 4; ++nt) {
        int col = col0 + wn + (nt << 4) + li;
        float v = bf2f(out1[lt * Fc + col]) + mb[col] * (acc[mt][nt][r] + b2[col]);
        long oi = (tok_base + lt) * Fc + col;
        if (bf) ((u16*)dout)[oi] = f2bf(v);
        else    ((float*)dout)[oi] = v;
      }
    }
  }
}

extern "C" void kernel_launch(void* const* d_in, const int* in_sizes, int n_in,
                              void* d_out, int out_size, void* d_ws, size_t ws_size,
                              hipStream_t stream) {
  char* ws = (char*)d_ws;
  size_t off = 0;
  auto alloc = [&](size_t bytes) -> char* {
    char* p = ws + off;
    off += (bytes + 255) & ~(size_t)255;
    return p;
  };
  int*   flag = (int*)  alloc(4);
  float* mods = (float*)alloc((size_t)Bc * SIXF * 4);
  float* Abar = (float*)alloc(2 * Nc * 2 * 4);
  float* pbf  = (float*)alloc(Fc * 4);
  float* b1f  = (float*)alloc(Hc * 4);
  float* b2f  = (float*)alloc(Fc * 4);
  u16* Wbup = (u16*)alloc((size_t)Fc * 256 * 2);
  u16* Gp   = (u16*)alloc((size_t)256 * Fc * 2);
  u16* P2p  = (u16*)alloc((size_t)Fc * Fc * 2);
  u16* W1p  = (u16*)alloc((size_t)Fc * Hc * 2);
  u16* W2p  = (u16*)alloc((size_t)Hc * Fc * 2);
  u16* pwp  = (u16*)alloc((size_t)1024 * Fc * 2);
  u16* Cpm  = (u16*)alloc((size_t)256 * Fc * 2);
  size_t off_static = off;

  const size_t U = (size_t)Sc * Fc * 2;   // 8.39 MB per batch unit
  int nb = 4;
  while (nb > 1 && off_static + (size_t)nb * 4 * U + 4096 > ws_size) nb >>= 1;

  u16*   h    = (u16*)  alloc((size_t)nb * U);            // also tbuf chunk
  float* Bu   = (float*)alloc((size_t)nb * U);            // also h2
  u16*   xh   = (u16*)  alloc((size_t)nb * U / 2);
  u16*   xl   = (u16*)  alloc((size_t)nb * U / 2);
  u16*   out1 = (u16*)  alloc((size_t)nb * U);
  u16* tch = h;
  u16* h2  = (u16*)Bu;

  // detection + scalar conversions
  k_detect<<<1, 64, 0, stream>>>((const u16*)d_in[0], flag);
  k_convert<<<2, 256, 0, stream>>>(d_in[19], pbf, Fc, flag);
  k_convert<<<8, 256, 0, stream>>>(d_in[23], b1f, Hc, flag);
  k_convert<<<2, 256, 0, stream>>>(d_in[25], b2f, Fc, flag);
  // mods
  k_mods_init<<<12, 256, 0, stream>>>(d_in[21], flag, mods);
  k_mods2<<<dim3(12, Bc, 4), 256, 0, stream>>>(d_in[1], d_in[20], flag, mods);
  // S5 weights
  k_prep<<<dim3(2, 8), 64, 0, stream>>>(d_in[2], d_in[3], d_in[4], d_in[5], d_in[9],
                                        d_in[10], d_in[11], d_in[12], d_in[13], d_in[17],
                                        flag, Wbup, Abar);
  k_P2p<<<(Fc * Fc) / 256, 256, 0, stream>>>(d_in[8], d_in[16], d_in[18], flag, P2p);
  // G via MFMA: pack proj_w (1024x512) + build Cpm, then GEMM
  k_Wpack<<<256, 256, 0, stream>>>(d_in[18], flag, 9, pwp);
  k_Cpm<<<256, 256, 0, stream>>>(d_in[6], d_in[7], d_in[14], d_in[15], flag, Cpm);
  k_Gp2<<<dim3(4, 2), 256, 0, stream>>>(Cpm, pwp, Gp);
  // MLP weights
  k_Wpack<<<512, 256, 0, stream>>>(d_in[22], flag, 11, W1p);
  k_Wpack<<<512, 256, 0, stream>>>(d_in[24], flag, 9, W2p);

  for (int b0 = 0; b0 < Bc; b0 += nb) {
    long tok_base = (long)b0 * Sc;
    long rows = (long)nb * Sc;
    k_ln<<<rows, 256, 0, stream>>>(d_in[0], 0, tok_base, b0, flag, mods, 0, Fc, h);
    k_gemm_bu<<<dim3(2, rows / 128), 256, 0, stream>>>(h, Wbup, nb, Bu);
    k_scan<<<2 * nb * 64, 256, 0, stream>>>(Bu, Abar, nb);
    k_xs_t<<<rows / 32, 256, 0, stream>>>(Bu, nb, xh, xl);
    k_gemm_y<<<dim3(Fc / 128, rows / 128), 256, 0, stream>>>(xh, xl, Gp, h, P2p,
                                                             d_in[0], tok_base, b0, flag, mods, pbf, out1);
    k_ln<<<rows, 256, 0, stream>>>(out1, 1, 0, b0, flag, mods, 3 * Fc, 4 * Fc, h2);
    long RC = rows / 4;
    for (int ch = 0; ch < 4; ++ch) {
      long crow0 = ch * RC;
      k_mlp1<<<dim3(Hc / 128, RC / 128), 256, 0, stream>>>(h2, W1p, b1f, crow0, tch);
      k_mlp2<<<dim3(Fc / 128, RC / 128), 256, 0, stream>>>(tch, W2p, b2f, out1, mods, crow0,
                                                           tok_base, b0, flag, d_out);
    }
  }
  (void)n_in; (void)out_size; (void)in_sizes;
}